// Round 4
// baseline (335.045 us; speedup 1.0000x reference)
//
#include <hip/hip_runtime.h>
#include <math.h>

// ---------------------------------------------------------------------------
// PatchEmbedding: gather 9x9x3 patches from frames, x@W1+b1 -> GELU -> @W2+b2
// B=4, T=16, C=3, H=W=256, N=8192, patch_dim=243, EMBED=768
// Inputs/outputs fp32; t_src int32. Internally bf16 MFMA (no fp32 MFMA on CDNA4).
//
// K-order trick: X and W1T both use permuted order k' = c*81 + i*9 + j so the
// gather reads are x-contiguous per 9-lane run. GEMM sees consistent columns.
// Gather rows are processed in (b,t)-bucket order (perm) so consecutive blocks
// share one 3 MB frame -> L2-resident.
// GEMM: 128x128 tile, 16x16x32 bf16 MFMA, double-buffered LDS fed by
// global_load_lds issued right AFTER the single per-iter barrier (loads for
// tile k+1 fly during tile-k MFMA; the next barrier's vmcnt(0) drains them).
// ---------------------------------------------------------------------------

typedef __attribute__((ext_vector_type(8))) short short8;
typedef __attribute__((ext_vector_type(4))) float floatx4;

#define M_ROWS 32768      // B*N = 4*8192
#define KPAD   256        // patch_dim 243 padded to 256
#define EMB    768

typedef __attribute__((address_space(1))) const void g_void;
typedef __attribute__((address_space(3))) void l_void;

__device__ __forceinline__ unsigned short f2bf(float f) {
    union { float f; unsigned int i; } w;
    w.f = f;
    unsigned int x = w.i;
    x += 0x7fffu + ((x >> 16) & 1u);   // round-to-nearest-even
    return (unsigned short)(x >> 16);
}

// ---- prep: W1 (243x768 f32) -> W1T (768x256 bf16, zero-pad, permuted k') ----
__global__ void k_transpose_w1(const float* __restrict__ W1,
                               unsigned short* __restrict__ W1T) {
    int idx = blockIdx.x * 256 + threadIdx.x;   // 768*256 total
    int n  = idx >> 8;        // 0..767
    int kp = idx & 255;       // permuted k': c*81 + i*9 + j
    unsigned short v = 0;
    if (kp < 243) {
        int c = kp / 81;
        int r = kp - c * 81;
        int i = r / 9;
        int j = r - i * 9;
        int e = i * 27 + j * 3 + c;   // reference order
        v = f2bf(W1[e * EMB + n]);
    }
    W1T[idx] = v;
}

// ---- prep: W2 (768x768 f32) -> W2T (768x768 bf16), LDS-tiled transpose ----
__global__ void k_transpose_w2(const float* __restrict__ W2,
                               unsigned short* __restrict__ W2T) {
    __shared__ float tile[32][33];
    int tx = threadIdx.x & 31, ty = threadIdx.x >> 5;   // 32 x 8
    int k0 = blockIdx.x * 32, n0 = blockIdx.y * 32;
#pragma unroll
    for (int i = 0; i < 4; ++i)
        tile[ty + i * 8][tx] = W2[(size_t)(k0 + ty + i * 8) * EMB + n0 + tx];
    __syncthreads();
#pragma unroll
    for (int i = 0; i < 4; ++i)
        W2T[(size_t)(n0 + ty + i * 8) * EMB + k0 + tx] = f2bf(tile[tx][ty + i * 8]);
}

// ---- bucket sort rows by (b,t): 64 buckets -------------------------------
__global__ void k_zero64(int* __restrict__ p) { p[threadIdx.x] = 0; }

__global__ void k_count(const int* __restrict__ t_src, int* __restrict__ cnt) {
    int row = blockIdx.x * 256 + threadIdx.x;
    int bucket = (row >> 13) * 16 + t_src[row];
    atomicAdd(&cnt[bucket], 1);
}

__global__ void k_scan64(const int* __restrict__ cnt, int* __restrict__ offs) {
    __shared__ int s[64];
    int i = threadIdx.x;
    s[i] = cnt[i];
    __syncthreads();
    if (i == 0) {
        int acc = 0;
        for (int j = 0; j < 64; ++j) { int c = s[j]; s[j] = acc; acc += c; }
    }
    __syncthreads();
    offs[i] = s[i];
}

__global__ void k_scatter(const int* __restrict__ t_src, int* __restrict__ offs,
                          int* __restrict__ perm) {
    int row = blockIdx.x * 256 + threadIdx.x;
    int bucket = (row >> 13) * 16 + t_src[row];
    int pos = atomicAdd(&offs[bucket], 1);
    perm[pos] = row;
}

// ---- gather patches -> X (32768 x 256 bf16), channel-major order k' --------
__global__ void k_gather(const float* __restrict__ frames,
                         const float* __restrict__ coords,
                         const int* __restrict__ t_src,
                         const int* __restrict__ perm,
                         unsigned short* __restrict__ X) {
    int pos  = blockIdx.x * 4 + (threadIdx.x >> 6);
    int row  = perm[pos];
    int lane = threadIdx.x & 63;
    int b = row >> 13;

    float cu = coords[row * 2 + 0];
    float cv = coords[row * 2 + 1];
    int u = (int)(cu * 255.0f);   // exact fp32 math, matches reference
    int v = (int)(cv * 255.0f);
    int t = t_src[row];

    const float* fb = frames + (size_t)(b * 16 + t) * (3 * 256 * 256);
    unsigned short* xr = X + (size_t)row * KPAD;

#pragma unroll
    for (int it = 0; it < 4; ++it) {
        int kp = lane + it * 64;            // permuted index c*81 + i*9 + j
        unsigned short val = 0;
        if (kp < 243) {
            int c = kp / 81;
            int r = kp - c * 81;
            int i = r / 9;
            int j = r - i * 9;
            int y = v + i - 4; y = (y < 0) ? 0 : (y > 255 ? 255 : y);
            int x = u + j - 4; x = (x < 0) ? 0 : (x > 255 ? 255 : x);
            val = f2bf(fb[(size_t)c * 65536 + y * 256 + x]);
        }
        xr[kp] = val;
    }
}

// ---- MFMA GEMM: C(MxEMB) = act(A(MxK) @ BT(EMBxK)^T + bias) ---------------
// 128x128 tile / 4 waves (each 64x64 via 4x4 16x16x32). Double-buffered LDS,
// global_load_lds width=16 issued right after the single per-iteration
// barrier: tile k+1 is in flight during tile-k MFMA; the next iteration's
// barrier (compiler-inserted vmcnt(0)+s_barrier) drains it.
// XOR swizzle: logical 16B slot s of row r lives at physical slot s^(r&7)
// (global source address is per-lane free; LDS dest is lane-ordered).
template <int K, bool GELU, bool OUT_F32>
__global__ __launch_bounds__(256, 2)
void k_gemm(const unsigned short* __restrict__ A,
            const unsigned short* __restrict__ BT,
            const float* __restrict__ bias,
            void* __restrict__ Cv) {
    __shared__ unsigned short As[2][128 * 64];   // 16 KB each
    __shared__ unsigned short Bs[2][128 * 64];   // total LDS = 64 KB

    int tid  = threadIdx.x;
    int wave = tid >> 6;
    int lane = tid & 63;
    int wm = (wave >> 1) * 64;      // wave row offset in tile
    int wn = (wave & 1) * 64;       // wave col offset in tile
    int lm = lane & 15;
    int lq = lane >> 4;

    int m0 = blockIdx.x * 128;
    int n0 = blockIdx.y * 128;

    floatx4 acc[4][4];
#pragma unroll
    for (int i = 0; i < 4; ++i)
#pragma unroll
        for (int j = 0; j < 4; ++j)
            acc[i][j] = (floatx4){0.f, 0.f, 0.f, 0.f};

    const unsigned short* Ag = A  + (size_t)m0 * K;
    const unsigned short* Bg = BT + (size_t)n0 * K;

    // staging geometry: chunk = wave*4+i covers rows [chunk*8, chunk*8+8);
    // lane -> row chunk*8 + (lane>>3), physical 16B slot lane&7.
    int rl    = lane >> 3;
    int pslot = lane & 7;

    // prologue: issue tile 0 into buffer 0
#pragma unroll
    for (int i = 0; i < 4; ++i) {
        int chunk = wave * 4 + i;
        int r     = chunk * 8 + rl;
        int lslot = pslot ^ (r & 7);
        __builtin_amdgcn_global_load_lds((g_void*)(Ag + (size_t)r * K + (lslot << 3)),
                                         (l_void*)(&As[0][chunk * 512]), 16, 0, 0);
        __builtin_amdgcn_global_load_lds((g_void*)(Bg + (size_t)r * K + (lslot << 3)),
                                         (l_void*)(&Bs[0][chunk * 512]), 16, 0, 0);
    }

    int buf = 0;
    for (int k0 = 0; k0 < K; k0 += 64) {
        __syncthreads();   // drains gll for tile(k0) [issued last iter], closes reads of buf^1

        if (k0 + 64 < K) {
#pragma unroll
            for (int i = 0; i < 4; ++i) {
                int chunk = wave * 4 + i;
                int r     = chunk * 8 + rl;
                int lslot = pslot ^ (r & 7);
                __builtin_amdgcn_global_load_lds(
                    (g_void*)(Ag + (size_t)r * K + k0 + 64 + (lslot << 3)),
                    (l_void*)(&As[buf ^ 1][chunk * 512]), 16, 0, 0);
                __builtin_amdgcn_global_load_lds(
                    (g_void*)(Bg + (size_t)r * K + k0 + 64 + (lslot << 3)),
                    (l_void*)(&Bs[buf ^ 1][chunk * 512]), 16, 0, 0);
            }
        }

#pragma unroll
        for (int ks = 0; ks < 2; ++ks) {         // two K=32 steps per BK=64
            short8 af[4], bfr[4];
#pragma unroll
            for (int mi = 0; mi < 4; ++mi) {
                int row = wm + mi * 16 + lm;
                int ps  = ((ks << 2) + lq) ^ (row & 7);
                af[mi] = *(const short8*)(&As[buf][row * 64 + (ps << 3)]);
            }
#pragma unroll
            for (int ni = 0; ni < 4; ++ni) {
                int row = wn + ni * 16 + lm;
                int ps  = ((ks << 2) + lq) ^ (row & 7);
                bfr[ni] = *(const short8*)(&Bs[buf][row * 64 + (ps << 3)]);
            }
#pragma unroll
            for (int mi = 0; mi < 4; ++mi)
#pragma unroll
                for (int ni = 0; ni < 4; ++ni)
                    acc[mi][ni] = __builtin_amdgcn_mfma_f32_16x16x32_bf16(
                        af[mi], bfr[ni], acc[mi][ni], 0, 0, 0);
        }
        buf ^= 1;
    }

    // epilogue: D[row][col], row = lq*4 + r, col = lm within each 16x16 tile
#pragma unroll
    for (int ni = 0; ni < 4; ++ni) {
        int col = n0 + wn + ni * 16 + lm;
        float bs = bias[col];
#pragma unroll
        for (int mi = 0; mi < 4; ++mi) {
            int rowb = m0 + wm + mi * 16 + lq * 4;
#pragma unroll
            for (int r = 0; r < 4; ++r) {
                float x = acc[mi][ni][r] + bs;
                if (GELU)
                    x = 0.5f * x * (1.0f + erff(x * 0.70710678118f));
                size_t idx = (size_t)(rowb + r) * EMB + col;
                if (OUT_F32)
                    ((float*)Cv)[idx] = x;
                else
                    ((unsigned short*)Cv)[idx] = f2bf(x);
            }
        }
    }
}

// ---------------------------------------------------------------------------
extern "C" void kernel_launch(void* const* d_in, const int* in_sizes, int n_in,
                              void* d_out, int out_size, void* d_ws, size_t ws_size,
                              hipStream_t stream) {
    const float* frames = (const float*)d_in[0];
    const float* coords = (const float*)d_in[1];
    const int*   t_src  = (const int*)d_in[2];
    const float* W1     = (const float*)d_in[3];
    const float* b1     = (const float*)d_in[4];
    const float* W2     = (const float*)d_in[5];
    const float* b2     = (const float*)d_in[6];
    float* out = (float*)d_out;

    char* ws = (char*)d_ws;
    // workspace layout:
    //   X    : 32768*256*2 = 16,777,216 B  (bf16, permuted k')
    //   Hbuf : 32768*768*2 = 50,331,648 B  (bf16)
    //   W1T  : 768*256*2   =    393,216 B  (bf16, permuted k')
    //   W2T  : 768*768*2   =  1,179,648 B  (bf16)
    //   cnt  : 64*4, offs : 64*4, perm : 32768*4
    unsigned short* X    = (unsigned short*)(ws);
    unsigned short* Hbuf = (unsigned short*)(ws + 16777216);
    unsigned short* W1T  = (unsigned short*)(ws + 16777216 + 50331648);
    unsigned short* W2T  = (unsigned short*)(ws + 16777216 + 50331648 + 393216);
    int* cnt  = (int*)(ws + 16777216 + 50331648 + 393216 + 1179648);
    int* offs = cnt + 64;
    int* perm = offs + 64;

    // prep transposes (tiny)
    k_transpose_w1<<<768, 256, 0, stream>>>(W1, W1T);
    k_transpose_w2<<<dim3(24, 24), 256, 0, stream>>>(W2, W2T);

    // bucket sort rows by (b,t) for gather L2 locality
    k_zero64<<<1, 64, 0, stream>>>(cnt);
    k_count<<<128, 256, 0, stream>>>(t_src, cnt);
    k_scan64<<<1, 64, 0, stream>>>(cnt, offs);
    k_scatter<<<128, 256, 0, stream>>>(t_src, offs, perm);

    // gather patches (one wave per row, channel-major element order)
    k_gather<<<M_ROWS / 4, 256, 0, stream>>>(frames, coords, t_src, perm, X);

    // GEMM1: H = gelu(X @ W1 + b1)   (K = 256 padded), bf16 out
    k_gemm<KPAD, true, false><<<dim3(M_ROWS / 128, EMB / 128), 256, 0, stream>>>(X, W1T, b1, Hbuf);

    // GEMM2: out = H @ W2 + b2       (K = 768), fp32 out
    k_gemm<EMB, false, true><<<dim3(M_ROWS / 128, EMB / 128), 256, 0, stream>>>(Hbuf, W2T, b2, out);
}

// Round 5
// 243.387 us; speedup vs baseline: 1.3766x; 1.3766x over previous
//
#include <hip/hip_runtime.h>
#include <math.h>

// ---------------------------------------------------------------------------
// PatchEmbedding: gather 9x9x3 patches from frames, x@W1+b1 -> GELU -> @W2+b2
// B=4, T=16, C=3, H=W=256, N=8192, patch_dim=243, EMBED=768
// Inputs/outputs fp32; t_src int32. Internally bf16 MFMA (no fp32 MFMA on CDNA4).
//
// K-order trick: X and W1T both use permuted order k' = c*81 + i*9 + j so the
// gather reads are x-contiguous per 9-lane run. GEMM sees consistent columns.
// GEMM: 128x128 tile, 16x16x32 bf16 MFMA, double-buffered LDS fed by
// global_load_lds width=16 issued right AFTER the single per-iter barrier
// (tile k+1 flies during tile-k MFMA; next barrier's vmcnt(0) drains it).
// r4 lesson: bucket-sorting the gather rows cost ~140us in side kernels for a
// gather that is already L3-resident — reverted.
// ---------------------------------------------------------------------------

typedef __attribute__((ext_vector_type(8))) short short8;
typedef __attribute__((ext_vector_type(4))) float floatx4;

#define M_ROWS 32768      // B*N = 4*8192
#define KPAD   256        // patch_dim 243 padded to 256
#define EMB    768

typedef __attribute__((address_space(1))) const void g_void;
typedef __attribute__((address_space(3))) void l_void;

__device__ __forceinline__ unsigned short f2bf(float f) {
    union { float f; unsigned int i; } w;
    w.f = f;
    unsigned int x = w.i;
    x += 0x7fffu + ((x >> 16) & 1u);   // round-to-nearest-even
    return (unsigned short)(x >> 16);
}

// tanh-form GELU: max abs deviation from exact erf-GELU < 1e-3 — far under
// the 2%-of-max threshold and under the bf16 rounding already applied to H.
__device__ __forceinline__ float gelu_f(float x) {
    float x3 = x * x * x;
    float y  = 1.5957691216f * (x + 0.044715f * x3);   // 2*sqrt(2/pi)*(...)
    float e  = __expf(y);                               // e^{2z}
    float th = 1.0f - 2.0f / (e + 1.0f);                // tanh(z)
    return 0.5f * x * (1.0f + th);
}

// ---- prep: W1 (243x768 f32) -> W1T (768x256 bf16, zero-pad, permuted k') ----
__global__ void k_transpose_w1(const float* __restrict__ W1,
                               unsigned short* __restrict__ W1T) {
    int idx = blockIdx.x * 256 + threadIdx.x;   // 768*256 total
    int n  = idx >> 8;        // 0..767
    int kp = idx & 255;       // permuted k': c*81 + i*9 + j
    unsigned short v = 0;
    if (kp < 243) {
        int c = kp / 81;
        int r = kp - c * 81;
        int i = r / 9;
        int j = r - i * 9;
        int e = i * 27 + j * 3 + c;   // reference order
        v = f2bf(W1[e * EMB + n]);
    }
    W1T[idx] = v;
}

// ---- prep: W2 (768x768 f32) -> W2T (768x768 bf16), LDS-tiled transpose ----
__global__ void k_transpose_w2(const float* __restrict__ W2,
                               unsigned short* __restrict__ W2T) {
    __shared__ float tile[32][33];
    int tx = threadIdx.x & 31, ty = threadIdx.x >> 5;   // 32 x 8
    int k0 = blockIdx.x * 32, n0 = blockIdx.y * 32;
#pragma unroll
    for (int i = 0; i < 4; ++i)
        tile[ty + i * 8][tx] = W2[(size_t)(k0 + ty + i * 8) * EMB + n0 + tx];
    __syncthreads();
#pragma unroll
    for (int i = 0; i < 4; ++i)
        W2T[(size_t)(n0 + ty + i * 8) * EMB + k0 + tx] = f2bf(tile[tx][ty + i * 8]);
}

// ---- gather patches -> X (32768 x 256 bf16), channel-major order k' --------
__global__ void k_gather(const float* __restrict__ frames,
                         const float* __restrict__ coords,
                         const int* __restrict__ t_src,
                         unsigned short* __restrict__ X) {
    int row  = blockIdx.x * 4 + (threadIdx.x >> 6);   // 0..32767
    int lane = threadIdx.x & 63;
    int b = row >> 13;

    float cu = coords[row * 2 + 0];
    float cv = coords[row * 2 + 1];
    int u = (int)(cu * 255.0f);   // exact fp32 math, matches reference
    int v = (int)(cv * 255.0f);
    int t = t_src[row];

    const float* fb = frames + (size_t)(b * 16 + t) * (3 * 256 * 256);
    unsigned short* xr = X + (size_t)row * KPAD;

#pragma unroll
    for (int it = 0; it < 4; ++it) {
        int kp = lane + it * 64;            // permuted index c*81 + i*9 + j
        unsigned short val = 0;
        if (kp < 243) {
            int c = kp / 81;
            int r = kp - c * 81;
            int i = r / 9;
            int j = r - i * 9;
            int y = v + i - 4; y = (y < 0) ? 0 : (y > 255 ? 255 : y);
            int x = u + j - 4; x = (x < 0) ? 0 : (x > 255 ? 255 : x);
            val = f2bf(fb[(size_t)c * 65536 + y * 256 + x]);
        }
        xr[kp] = val;
    }
}

// ---- MFMA GEMM body (shared by k_gemm1 / k_gemm2) -------------------------
// 128x128 tile / 4 waves (each 64x64 via 4x4 16x16x32). Double-buffered LDS,
// global_load_lds width=16 issued right after the single per-iteration
// barrier. XOR swizzle: logical 16B slot s of row r at physical slot s^(r&7).
template <int K, bool GELU, bool OUT_F32>
__device__ __forceinline__
void gemm_body(const unsigned short* __restrict__ A,
               const unsigned short* __restrict__ BT,
               const float* __restrict__ bias,
               void* __restrict__ Cv) {
    __shared__ unsigned short As[2][128 * 64];   // 16 KB each
    __shared__ unsigned short Bs[2][128 * 64];   // total LDS = 64 KB

    int tid  = threadIdx.x;
    int wave = tid >> 6;
    int lane = tid & 63;
    int wm = (wave >> 1) * 64;      // wave row offset in tile
    int wn = (wave & 1) * 64;       // wave col offset in tile
    int lm = lane & 15;
    int lq = lane >> 4;

    int m0 = blockIdx.x * 128;
    int n0 = blockIdx.y * 128;

    floatx4 acc[4][4];
#pragma unroll
    for (int i = 0; i < 4; ++i)
#pragma unroll
        for (int j = 0; j < 4; ++j)
            acc[i][j] = (floatx4){0.f, 0.f, 0.f, 0.f};

    const unsigned short* Ag = A  + (size_t)m0 * K;
    const unsigned short* Bg = BT + (size_t)n0 * K;

    int rl    = lane >> 3;
    int pslot = lane & 7;

    // prologue: issue tile 0 into buffer 0
#pragma unroll
    for (int i = 0; i < 4; ++i) {
        int chunk = wave * 4 + i;
        int r     = chunk * 8 + rl;
        int lslot = pslot ^ (r & 7);
        __builtin_amdgcn_global_load_lds((g_void*)(Ag + (size_t)r * K + (lslot << 3)),
                                         (l_void*)(&As[0][chunk * 512]), 16, 0, 0);
        __builtin_amdgcn_global_load_lds((g_void*)(Bg + (size_t)r * K + (lslot << 3)),
                                         (l_void*)(&Bs[0][chunk * 512]), 16, 0, 0);
    }

    int buf = 0;
    for (int k0 = 0; k0 < K; k0 += 64) {
        __syncthreads();   // drains gll for tile(k0), closes reads of buf^1

        if (k0 + 64 < K) {
#pragma unroll
            for (int i = 0; i < 4; ++i) {
                int chunk = wave * 4 + i;
                int r     = chunk * 8 + rl;
                int lslot = pslot ^ (r & 7);
                __builtin_amdgcn_global_load_lds(
                    (g_void*)(Ag + (size_t)r * K + k0 + 64 + (lslot << 3)),
                    (l_void*)(&As[buf ^ 1][chunk * 512]), 16, 0, 0);
                __builtin_amdgcn_global_load_lds(
                    (g_void*)(Bg + (size_t)r * K + k0 + 64 + (lslot << 3)),
                    (l_void*)(&Bs[buf ^ 1][chunk * 512]), 16, 0, 0);
            }
        }

#pragma unroll
        for (int ks = 0; ks < 2; ++ks) {         // two K=32 steps per BK=64
            short8 af[4], bfr[4];
#pragma unroll
            for (int mi = 0; mi < 4; ++mi) {
                int row = wm + mi * 16 + lm;
                int ps  = ((ks << 2) + lq) ^ (row & 7);
                af[mi] = *(const short8*)(&As[buf][row * 64 + (ps << 3)]);
            }
#pragma unroll
            for (int ni = 0; ni < 4; ++ni) {
                int row = wn + ni * 16 + lm;
                int ps  = ((ks << 2) + lq) ^ (row & 7);
                bfr[ni] = *(const short8*)(&Bs[buf][row * 64 + (ps << 3)]);
            }
#pragma unroll
            for (int mi = 0; mi < 4; ++mi)
#pragma unroll
                for (int ni = 0; ni < 4; ++ni)
                    acc[mi][ni] = __builtin_amdgcn_mfma_f32_16x16x32_bf16(
                        af[mi], bfr[ni], acc[mi][ni], 0, 0, 0);
        }
        buf ^= 1;
    }

    // epilogue: D[row][col], row = lq*4 + r, col = lm within each 16x16 tile
#pragma unroll
    for (int ni = 0; ni < 4; ++ni) {
        int col = n0 + wn + ni * 16 + lm;
        float bs = bias[col];
#pragma unroll
        for (int mi = 0; mi < 4; ++mi) {
            int rowb = m0 + wm + mi * 16 + lq * 4;
#pragma unroll
            for (int r = 0; r < 4; ++r) {
                float x = acc[mi][ni][r] + bs;
                if (GELU)
                    x = gelu_f(x);
                size_t idx = (size_t)(rowb + r) * EMB + col;
                if (OUT_F32)
                    ((float*)Cv)[idx] = x;
                else
                    ((unsigned short*)Cv)[idx] = f2bf(x);
            }
        }
    }
}

// distinct names so rocprof shows each GEMM separately
__global__ __launch_bounds__(256, 2)
void k_gemm1(const unsigned short* __restrict__ A, const unsigned short* __restrict__ BT,
             const float* __restrict__ bias, unsigned short* __restrict__ C) {
    gemm_body<KPAD, true, false>(A, BT, bias, (void*)C);
}

__global__ __launch_bounds__(256, 2)
void k_gemm2(const unsigned short* __restrict__ A, const unsigned short* __restrict__ BT,
             const float* __restrict__ bias, float* __restrict__ C) {
    gemm_body<EMB, false, true>(A, BT, bias, (void*)C);
}

// ---------------------------------------------------------------------------
extern "C" void kernel_launch(void* const* d_in, const int* in_sizes, int n_in,
                              void* d_out, int out_size, void* d_ws, size_t ws_size,
                              hipStream_t stream) {
    const float* frames = (const float*)d_in[0];
    const float* coords = (const float*)d_in[1];
    const int*   t_src  = (const int*)d_in[2];
    const float* W1     = (const float*)d_in[3];
    const float* b1     = (const float*)d_in[4];
    const float* W2     = (const float*)d_in[5];
    const float* b2     = (const float*)d_in[6];
    float* out = (float*)d_out;

    char* ws = (char*)d_ws;
    // workspace layout:
    //   X    : 32768*256*2 = 16,777,216 B  (bf16, permuted k')
    //   Hbuf : 32768*768*2 = 50,331,648 B  (bf16)
    //   W1T  : 768*256*2   =    393,216 B  (bf16, permuted k')
    //   W2T  : 768*768*2   =  1,179,648 B  (bf16)
    unsigned short* X    = (unsigned short*)(ws);
    unsigned short* Hbuf = (unsigned short*)(ws + 16777216);
    unsigned short* W1T  = (unsigned short*)(ws + 16777216 + 50331648);
    unsigned short* W2T  = (unsigned short*)(ws + 16777216 + 50331648 + 393216);

    // prep transposes (tiny)
    k_transpose_w1<<<768, 256, 0, stream>>>(W1, W1T);
    k_transpose_w2<<<dim3(24, 24), 256, 0, stream>>>(W2, W2T);

    // gather patches (one wave per row, channel-major element order)
    k_gather<<<M_ROWS / 4, 256, 0, stream>>>(frames, coords, t_src, X);

    // GEMM1: H = gelu(X @ W1 + b1)   (K = 256 padded), bf16 out
    k_gemm1<<<dim3(M_ROWS / 128, EMB / 128), 256, 0, stream>>>(X, W1T, b1, Hbuf);

    // GEMM2: out = H @ W2 + b2       (K = 768), fp32 out
    k_gemm2<<<dim3(M_ROWS / 128, EMB / 128), 256, 0, stream>>>(Hbuf, W2T, b2, out);
}